// Round 4
// baseline (33497.406 us; speedup 1.0000x reference)
//
#include <hip/hip_runtime.h>

// ---------------- problem constants ----------------
constexpr int SEQ = 2048;
constexpr int HD  = 512;     // H = D = DW
constexpr int TH3 = 1536;    // 3H
constexpr int ZT  = 3072;    // combined [W_hh | Ww_hh] output cols
constexpr int KWW = 3;

constexpr int GRID = 128;    // scan blocks (1 per CU, 128 <= 256 CUs -> co-resident)
constexpr int NT   = 512;    // threads/block (8 waves)
constexpr int ZB   = ZT / GRID;   // 24 z-cols per block
constexpr int HB   = HD / GRID;   // 4 h (aW_hh cols / zdot slice) per block
constexpr int SPB  = SEQ / GRID;  // 16 steps/block for metadata precompute
constexpr int MAXW = 16;          // max words ending at one step (validated <=16 by R2/R3 pass)

// ws layout (bytes)
constexpr size_t WS_FLAGS  = 0;          // 128 ints, barrier flags
constexpr size_t WS_CNT    = 1024;       // dtype-detect counter
constexpr size_t WS_Z      = 2048;       // 2 x 3072 f32 (double-buffered z)
constexpr size_t WS_ZEROSZ = 28672;      // memset region (flags+cnt+z)
constexpr size_t WS_ZDOT   = 28672;                        // 8*3*512 f32 dot ring
constexpr size_t WS_MHDR   = WS_ZDOT + (size_t)8*KWW*HD*4; // 2048 i32
constexpr size_t WS_MROWS  = WS_MHDR + (size_t)SEQ*4;      // 2048*16 i32
constexpr size_t WS_WIB    = ((WS_MROWS + (size_t)SEQ*MAXW*4 + 255)/256)*256;
constexpr size_t WS_AWIB   = WS_WIB  + (size_t)SEQ*TH3*4;  // 2048*512 f32
constexpr size_t WS_WWIB   = WS_AWIB + (size_t)SEQ*HD*4;   // 6144*1536 f32
constexpr size_t WS_END    = WS_WWIB + (size_t)SEQ*KWW*TH3*4;

__device__ inline float bf2f(unsigned int u) {
    return __builtin_bit_cast(float, u << 16);
}
__device__ inline unsigned short f2bf(float f) {
    unsigned int u = __builtin_bit_cast(unsigned int, f);
    u += 0x7fffu + ((u >> 16) & 1u);   // RNE
    return (unsigned short)(u >> 16);
}
__device__ inline float sigf(float x) { return 1.0f / (1.0f + expf(-x)); }

// LLC-coherent (agent-scope relaxed) accesses: sc-flagged global ops that bypass
// the non-coherent L1/L2; LLC is the serialization point. No wbl2/inv walks.
template <typename T>
__device__ inline T ldg_a(const T* p) {
    return __hip_atomic_load((T*)p, __ATOMIC_RELAXED, __HIP_MEMORY_SCOPE_AGENT);
}
template <typename T>
__device__ inline void stg_a(T* p, T v) {
    __hip_atomic_store(p, v, __ATOMIC_RELAXED, __HIP_MEMORY_SCOPE_AGENT);
}

// dual-dtype loads: mode=1 -> bf16 storage, mode=0 -> f32 storage
__device__ inline float4 ld4e(const void* p, size_t eoff, int mode) {
    if (mode) {
        uint2 v = *(const uint2*)((const unsigned short*)p + eoff);
        return make_float4(bf2f(v.x & 0xffffu), bf2f(v.x >> 16),
                           bf2f(v.y & 0xffffu), bf2f(v.y >> 16));
    }
    return *(const float4*)((const float*)p + eoff);
}
__device__ inline float ld1e(const void* p, size_t eoff, int mode) {
    return mode ? bf2f((unsigned int)((const unsigned short*)p)[eoff])
                : ((const float*)p)[eoff];
}

// ---------------- dtype detection ----------------
constexpr int NDET = 4096;
__global__ void detect_kernel(const unsigned int* __restrict__ w, int* __restrict__ cnt) {
    int local = 0;
    for (int i = threadIdx.x; i < NDET; i += 256) {
        unsigned int e = (w[i] >> 7) & 0xffu;
        if (e >= 90u && e <= 140u) local++;
    }
    atomicAdd(cnt, local);
}

// ---------------- precompute GEMM: C[M,N] = gather(A)[M,K] @ B[K,N] + bias ----------------
template<bool GATHER>
__global__ __launch_bounds__(256) void gemm_bias_kernel(
    const void* __restrict__ A, const void* __restrict__ B,
    const void* __restrict__ bias, const int* __restrict__ ids,
    const int* __restrict__ cnt,
    float* __restrict__ C, int M, int N, int K)
{
    const int mode = (*cnt > NDET / 2) ? 1 : 0;
    __shared__ __align__(16) float As[16][68];
    __shared__ __align__(16) float Bs[16][68];
    const int tid = threadIdx.x;
    const int ty = tid >> 4, tx = tid & 15;
    const int m0 = blockIdx.y * 64, n0 = blockIdx.x * 64;
    const int lrow = tid >> 2;
    const int kq   = (tid & 3) * 4;
    const int arow = m0 + lrow;
    const size_t abase = (GATHER ? (size_t)ids[arow] : (size_t)arow) * (size_t)K;
    const int brow = tid >> 4;
    const int bc   = (tid & 15) * 4;
    const int bcol = n0 + bc;
    float acc[4][4] = {};
    for (int k0 = 0; k0 < K; k0 += 16) {
        float4 av = ld4e(A, abase + k0 + kq, mode);
        float4 bv = ld4e(B, (size_t)(k0 + brow) * N + bcol, mode);
        As[kq + 0][lrow] = av.x;
        As[kq + 1][lrow] = av.y;
        As[kq + 2][lrow] = av.z;
        As[kq + 3][lrow] = av.w;
        Bs[brow][bc + 0] = bv.x;
        Bs[brow][bc + 1] = bv.y;
        Bs[brow][bc + 2] = bv.z;
        Bs[brow][bc + 3] = bv.w;
        __syncthreads();
        #pragma unroll
        for (int kk = 0; kk < 16; ++kk) {
            float a[4], bb[4];
            #pragma unroll
            for (int u = 0; u < 4; ++u) a[u] = As[kk][ty * 4 + u];
            #pragma unroll
            for (int v = 0; v < 4; ++v) bb[v] = Bs[kk][tx * 4 + v];
            #pragma unroll
            for (int u = 0; u < 4; ++u)
                #pragma unroll
                for (int v = 0; v < 4; ++v)
                    acc[u][v] = fmaf(a[u], bb[v], acc[u][v]);
        }
        __syncthreads();
    }
    float4 bsv = ld4e(bias, (size_t)(n0 + tx * 4), mode);
    #pragma unroll
    for (int u = 0; u < 4; ++u) {
        float4 o;
        o.x = acc[u][0] + bsv.x; o.y = acc[u][1] + bsv.y;
        o.z = acc[u][2] + bsv.z; o.w = acc[u][3] + bsv.w;
        *(float4*)(C + (size_t)(m0 + ty * 4 + u) * N + n0 + tx * 4) = o;
    }
}

// ---------------- flag-array barrier: no atomic RMWs ----------------
// Each block sc-stores its step number to flags[b]; wave 0 polls all 128 flags
// with 2 pipelined sc-loads/lane. No same-address RMW serialization.
__device__ inline void gbar(int* flags, int b, int k) {
    __atomic_signal_fence(__ATOMIC_SEQ_CST);
    __builtin_amdgcn_s_waitcnt(0);       // drain this wave's stores to LLC
    __syncthreads();                     // all waves drained
    const int tid = threadIdx.x;
    if (tid < 64) {
        if (tid == 0) stg_a(&flags[b], k);
        const int i0 = tid * 2;
        for (;;) {
            int a = ldg_a(&flags[i0]);
            int c = ldg_a(&flags[i0 + 1]);
            if (__all(a >= k && c >= k)) break;
            __builtin_amdgcn_s_sleep(1);
        }
    }
    __syncthreads();
    __atomic_signal_fence(__ATOMIC_SEQ_CST);
}

__device__ inline float wave_red(float acc) {
    #pragma unroll
    for (int m = 1; m < 64; m <<= 1) acc += __shfl_xor(acc, m, 64);
    return acc;
}

// ---------------- persistent sequential scan: ONE barrier per step ----------------
__global__ __launch_bounds__(NT, 1) void lattice_scan(
    const void* __restrict__ W_hh, const void* __restrict__ Ww_hh,
    const void* __restrict__ aW_hh,
    const float* __restrict__ WIb, const float* __restrict__ AWIb,
    const float* __restrict__ WWIb,
    float* __restrict__ zbase, float* __restrict__ zdot,
    int* __restrict__ flags, const int* __restrict__ cnt,
    const int* __restrict__ gpos, const int* __restrict__ gslot,
    const unsigned char* __restrict__ gmaskb,
    int* __restrict__ meta_hdr, int* __restrict__ meta_rows,
    void* __restrict__ outp, int Km)
{
    __shared__ __align__(16) unsigned short Wz[ZB][512]; // own z-cols of [W_hh|Ww_hh]
    __shared__ __align__(16) float Wa[HB][512];          // own 4 cols of aW_hh
    __shared__ __align__(16) float zl[ZT];               // staged z_{t-1}
    __shared__ __align__(16) float hL[HD], cL[HD];       // full local state
    __shared__ __align__(16) float ring[8][KWW][HD];     // local word-cell ring
    __shared__ __align__(16) float dotl[MAXW][HD];       // alpha-dots for step t
    __shared__ int mh_l[2], mr_l[2][MAXW];
    __shared__ int mfmt;

    const int b   = blockIdx.x;
    const int tid = threadIdx.x;
    const int wid = tid >> 6;
    const int q   = tid & 63;
    const int h   = tid;                 // NT == HD: thread <-> h channel
    const int mode = (*cnt > NDET / 2) ? 1 : 0;

    // ---- one-time init ----
    for (int idx = tid; idx < ZB * 512; idx += NT) {
        int c = idx % ZB, r = idx / ZB;
        int gz = b * ZB + c;
        float wv = (gz < TH3) ? ld1e(W_hh,  (size_t)r * TH3 + gz, mode)
                              : ld1e(Ww_hh, (size_t)r * TH3 + (gz - TH3), mode);
        Wz[c][r] = f2bf(wv);
    }
    for (int idx = tid; idx < HB * 512; idx += NT) {
        int ho = idx % HB, r = idx / HB;
        Wa[ho][r] = ld1e(aW_hh, (size_t)r * HD + b * HB + ho, mode);
    }
    for (int i = tid; i < HD; i += NT) { cL[i] = 0.f; hL[i] = 0.f; }
    if (tid == 0) mfmt = 0;
    __syncthreads();
    {   // mask storage width: nonzero byte at i%4!=0 => u8/bool storage
        int any = 0;
        int tot = SEQ * Km;
        for (int i = tid; i < tot; i += NT)
            if ((i & 3) && gmaskb[i]) any = 1;
        if (any) mfmt = 1;
    }
    __syncthreads();
    const int maskfmt = mfmt;
    const int* gmi = (const int*)gmaskb;

    // ---- one-time metadata precompute: rows packed (p<<2)|sl ----
    if (tid < SPB) {
        int t = b * SPB + tid;
        int nv = 0;
        for (int k = 0; k < Km; ++k) {
            int mv = maskfmt ? (int)gmaskb[t * Km + k] : gmi[t * Km + k];
            if (!mv) continue;
            int p = gpos[t * Km + k], sl = gslot[t * Km + k];
            if (p < 0 || p >= t || sl < 0 || sl >= KWW) continue; // defensive
            if (nv < MAXW) {
                stg_a(&meta_rows[t * MAXW + nv], (p << 2) | sl);
                nv++;
            }
        }
        stg_a(&meta_hdr[t], nv);
    }
    gbar(flags, b, 1);   // publish metadata

    // load meta for step 0 into LDS parity 0
    if (tid == 0) mh_l[0] = meta_hdr[0];
    if (tid < MAXW) mr_l[0][tid] = meta_rows[tid];
    __syncthreads();

    for (int t = 0; t < SEQ; ++t) {
        const int par = t & 1;
        const float* zr_ = zbase + ((t + 1) & 1) * ZT;   // z_{t-1}
        float*       zw_ = zbase + par * ZT;             // z_t
        const int rs = (t - 1) & 7;                      // ring slot for cells born at t-1

        // ===== stage A: issue ALL loads for this step in one window =====
        float zr[6];
        #pragma unroll
        for (int i = 0; i < 6; ++i) zr[i] = ldg_a(zr_ + i * 512 + tid);

        const int nv = mh_l[par];
        int   evs[MAXW];
        float dlr[MAXW];
        #pragma unroll
        for (int vi = 0; vi < MAXW; ++vi) {
            evs[vi] = (vi < nv) ? mr_l[par][vi] : -1;
            dlr[vi] = 0.f;
            if (vi < nv) {
                int p = evs[vi] >> 2, sl = evs[vi] & 3;
                if (p <= t - 2)   // far word: dot published at step p+1 <= t-1
                    dlr[vi] = ldg_a(&zdot[(size_t)(((p & 7) * KWW + sl)) * HD + h]);
            }
        }
        const float wir0 = WIb[(size_t)t * TH3 + h];
        const float wir1 = WIb[(size_t)t * TH3 + 512 + h];
        const float wir2 = WIb[(size_t)t * TH3 + 1024 + h];
        const float awr  = AWIb[(size_t)t * HD + h];
        float wwf[3], wwi[3], wwg[3];
        if (t > 0) {
            #pragma unroll
            for (int sl = 0; sl < 3; ++sl) {
                const float* wrow = WWIb + (size_t)((t - 1) * KWW + sl) * TH3;
                wwf[sl] = wrow[h]; wwi[sl] = wrow[512 + h]; wwg[sl] = wrow[1024 + h];
            }
        }
        // prefetch next step's metadata (immutable)
        if (t + 1 < SEQ) {
            if (tid == 0) mh_l[par ^ 1] = meta_hdr[t + 1];
            if (tid < MAXW) mr_l[par ^ 1][tid] = meta_rows[(size_t)(t + 1) * MAXW + tid];
        }

        // ===== stage B: land loads in LDS =====
        #pragma unroll
        for (int i = 0; i < 6; ++i) zl[i * 512 + tid] = zr[i];
        #pragma unroll
        for (int vi = 0; vi < MAXW; ++vi)
            if (vi < nv && (evs[vi] >> 2) <= t - 2) dotl[vi][h] = dlr[vi];
        __syncthreads();

        // ===== stage C: create word cells for start p = t-1 (all 3 slots) =====
        if (t > 0) {
            #pragma unroll
            for (int sl = 0; sl < 3; ++sl) {
                float cv = sigf(wwf[sl] + zl[1536 + h]) * cL[h]
                         + sigf(wwi[sl] + zl[2048 + h]) * tanhf(wwg[sl] + zl[2560 + h]);
                ring[rs][sl][h] = cv;
            }
        }
        __syncthreads();

        // ===== stage D: publish own dot-slices + local len-2 dots =====
        if (t > 0) {
            #pragma unroll
            for (int r = 0; r < 2; ++r) {
                int job = wid + 8 * r;
                if (job < 12) {
                    int sl = job >> 2, ho = job & 3;
                    const float* cp = &ring[rs][sl][0];
                    const float* wp = &Wa[ho][0];
                    float acc = 0.f;
                    #pragma unroll
                    for (int u = 0; u < 8; ++u) acc += cp[8 * q + u] * wp[8 * q + u];
                    acc = wave_red(acc);
                    if (q == 0)
                        stg_a(&zdot[(size_t)((rs * KWW + sl)) * HD + b * HB + ho], acc);
                }
            }
            // len-2 words ending at t: full local dot (rare, avg ~0.2/step)
            #pragma unroll
            for (int vi = 0; vi < MAXW; ++vi) {
                if (vi < nv && (evs[vi] >> 2) == t - 1) {
                    int sl = evs[vi] & 3;
                    float acc = 0.f;
                    for (int k = 0; k < HD; ++k)
                        acc += ring[rs][sl][k] * ld1e(aW_hh, (size_t)k * HD + h, mode);
                    dotl[vi][h] = acc;
                }
            }
        }
        __syncthreads();

        // ===== stage E: full h/c update (thread h) =====
        {
            float gi = sigf(zl[h] + wir0);
            float go = sigf(zl[512 + h] + wir1);
            float gg = tanhf(zl[1024 + h] + wir2);
            float c1;
            if (nv > 0) {
                float wiE = expf(gi);
                float num = wiE * gg, den = wiE;
                #pragma unroll
                for (int vi = 0; vi < MAXW; ++vi) {
                    if (vi < nv) {
                        int p = evs[vi] >> 2, sl = evs[vi] & 3;
                        float cin = ring[p & 7][sl][h];
                        float wa = expf(sigf(awr + dotl[vi][h]));
                        num += wa * cin;
                        den += wa;
                    }
                }
                c1 = num / den;
            } else {
                c1 = (1.f - gi) * cL[h] + gi * gg;
            }
            float h1 = go * tanhf(c1);
            cL[h] = c1;
            hL[h] = h1;
            if ((h >> 2) == b) {   // own output slice
                if (mode) {
                    unsigned short* o = (unsigned short*)outp;
                    o[(size_t)t * HD + h] = f2bf(h1);
                    o[(size_t)SEQ * HD + (size_t)t * HD + h] = f2bf(c1);
                } else {
                    float* o = (float*)outp;
                    o[(size_t)t * HD + h] = h1;
                    o[(size_t)SEQ * HD + (size_t)t * HD + h] = c1;
                }
            }
        }
        __syncthreads();

        // ===== stage F: z_t slice = h_t @ [W_hh|Ww_hh] (own 24 cols) =====
        #pragma unroll
        for (int j = 0; j < 3; ++j) {
            int c = wid * 3 + j;
            const float* hp = &hL[8 * q];
            uint4 wv = *(const uint4*)(&Wz[c][8 * q]);
            float acc = hp[0] * bf2f(wv.x & 0xffffu) + hp[1] * bf2f(wv.x >> 16)
                      + hp[2] * bf2f(wv.y & 0xffffu) + hp[3] * bf2f(wv.y >> 16)
                      + hp[4] * bf2f(wv.z & 0xffffu) + hp[5] * bf2f(wv.z >> 16)
                      + hp[6] * bf2f(wv.w & 0xffffu) + hp[7] * bf2f(wv.w >> 16);
            acc = wave_red(acc);
            if (q == 0) stg_a(&zw_[b * ZB + c], acc);
        }

        // ===== stage G: the single rendezvous =====
        gbar(flags, b, t + 2);
    }
}

extern "C" void kernel_launch(void* const* d_in, const int* in_sizes, int n_in,
                              void* d_out, int out_size, void* d_ws, size_t ws_size,
                              hipStream_t stream) {
    const void* x     = d_in[0];
    const void* W_ih  = d_in[1];
    const void* W_hh  = d_in[2];
    const void* bb    = d_in[3];
    const void* aW_ih = d_in[4];
    const void* aW_hh = d_in[5];
    const void* ab    = d_in[6];
    const void* Ww_ih = d_in[7];
    const void* Ww_hh = d_in[8];
    const void* bw    = d_in[9];
    const void* wemb  = d_in[10];
    const int* wids  = (const int*)d_in[11];
    const int* gpos  = (const int*)d_in[12];
    const int* gslot = (const int*)d_in[13];
    const unsigned char* gmask = (const unsigned char*)d_in[14];

    int Km = in_sizes[12] / SEQ;
    if (Km > 32) Km = 32;
    if (ws_size < WS_END) return;

    char* ws = (char*)d_ws;
    int*   flags = (int*)(ws + WS_FLAGS);
    int*   cnt   = (int*)(ws + WS_CNT);
    float* zbase = (float*)(ws + WS_Z);
    float* zdot  = (float*)(ws + WS_ZDOT);
    int*   mhdr  = (int*)(ws + WS_MHDR);
    int*   mrows = (int*)(ws + WS_MROWS);
    float* WIb   = (float*)(ws + WS_WIB);
    float* AWIb  = (float*)(ws + WS_AWIB);
    float* WWIb  = (float*)(ws + WS_WWIB);

    hipMemsetAsync(d_ws, 0, WS_ZEROSZ, stream);
    detect_kernel<<<1, 256, 0, stream>>>((const unsigned int*)W_ih, cnt);
    gemm_bias_kernel<false><<<dim3(TH3 / 64, SEQ / 64), 256, 0, stream>>>(
        x, W_ih, bb, nullptr, cnt, WIb, SEQ, TH3, HD);
    gemm_bias_kernel<false><<<dim3(HD / 64, SEQ / 64), 256, 0, stream>>>(
        x, aW_ih, ab, nullptr, cnt, AWIb, SEQ, HD, HD);
    gemm_bias_kernel<true><<<dim3(TH3 / 64, (SEQ * KWW) / 64), 256, 0, stream>>>(
        wemb, Ww_ih, bw, wids, cnt, WWIb, SEQ * KWW, TH3, HD);
    lattice_scan<<<GRID, NT, 0, stream>>>(
        W_hh, Ww_hh, aW_hh, WIb, AWIb, WWIb,
        zbase, zdot, flags, cnt,
        gpos, gslot, gmask, mhdr, mrows, d_out, Km);
}

// Round 5
// 15727.609 us; speedup vs baseline: 2.1298x; 2.1298x over previous
//
#include <hip/hip_runtime.h>

// ---------------- problem constants ----------------
constexpr int SEQ = 2048;
constexpr int HD  = 512;     // H = D = DW
constexpr int TH3 = 1536;    // 3H
constexpr int ZT  = 3072;    // combined [W_hh | Ww_hh] output cols
constexpr int KWW = 3;

constexpr int GRID = 64;     // scan blocks
constexpr int NT   = 512;    // threads/block (8 waves)
constexpr int HB   = HD / GRID;   // 8 h-channels per block
constexpr int ZC   = ZT / GRID;   // 48 z-cols per block (zeroing duty)
constexpr int NCOL = ZT / NT;     // 6 z-cols per thread (partial adds)
constexpr int SPB  = SEQ / GRID;  // 32 steps/block metadata precompute
constexpr int MAXW = 16;

// ws layout (bytes)
constexpr size_t WS_FLAGS  = 0;                     // 64 ints
constexpr size_t WS_CNT    = 1024;                  // dtype-detect counter
constexpr size_t WS_ZACC   = 2048;                  // 3 x 3072 f32 rotation
constexpr size_t WS_CS     = WS_ZACC + 3*ZT*4;      // 2 x 512 f32 c ring
constexpr size_t WS_ZEROSZ = WS_CS + 2*HD*4;        // memset region end
constexpr size_t WS_CBUF   = ((WS_ZEROSZ + 255)/256)*256;          // 6144*512 f32
constexpr size_t WS_MHDR   = WS_CBUF + (size_t)SEQ*KWW*HD*4;       // 2048 i32
constexpr size_t WS_MROWS  = WS_MHDR + (size_t)SEQ*4;              // 2048*16 i32
constexpr size_t WS_WIB    = WS_MROWS + (size_t)SEQ*MAXW*4;        // 2048*1536 f32
constexpr size_t WS_AWIB   = WS_WIB  + (size_t)SEQ*TH3*4;          // 2048*512 f32
constexpr size_t WS_WWIB   = WS_AWIB + (size_t)SEQ*HD*4;           // 6144*1536 f32
constexpr size_t WS_END    = WS_WWIB + (size_t)SEQ*KWW*TH3*4;

__device__ inline float bf2f(unsigned int u) {
    return __builtin_bit_cast(float, u << 16);
}
__device__ inline unsigned short f2bf(float f) {
    unsigned int u = __builtin_bit_cast(unsigned int, f);
    u += 0x7fffu + ((u >> 16) & 1u);   // RNE
    return (unsigned short)(u >> 16);
}
__device__ inline float sigf(float x) { return 1.0f / (1.0f + expf(-x)); }

// LLC-coherent (agent-scope relaxed) accesses: bypass non-coherent L1/L2.
template <typename T>
__device__ inline T ldg_a(const T* p) {
    return __hip_atomic_load((T*)p, __ATOMIC_RELAXED, __HIP_MEMORY_SCOPE_AGENT);
}
template <typename T>
__device__ inline void stg_a(T* p, T v) {
    __hip_atomic_store(p, v, __ATOMIC_RELAXED, __HIP_MEMORY_SCOPE_AGENT);
}

// dual-dtype loads: mode=1 -> bf16 storage, mode=0 -> f32 storage
__device__ inline float4 ld4e(const void* p, size_t eoff, int mode) {
    if (mode) {
        uint2 v = *(const uint2*)((const unsigned short*)p + eoff);
        return make_float4(bf2f(v.x & 0xffffu), bf2f(v.x >> 16),
                           bf2f(v.y & 0xffffu), bf2f(v.y >> 16));
    }
    return *(const float4*)((const float*)p + eoff);
}
__device__ inline float ld1e(const void* p, size_t eoff, int mode) {
    return mode ? bf2f((unsigned int)((const unsigned short*)p)[eoff])
                : ((const float*)p)[eoff];
}

// ---------------- dtype detection ----------------
constexpr int NDET = 4096;
__global__ void detect_kernel(const unsigned int* __restrict__ w, int* __restrict__ cnt) {
    int local = 0;
    for (int i = threadIdx.x; i < NDET; i += 256) {
        unsigned int e = (w[i] >> 7) & 0xffu;
        if (e >= 90u && e <= 140u) local++;
    }
    atomicAdd(cnt, local);
}

// ---------------- precompute GEMM: C[M,N] = gather(A)[M,K] @ B[K,N] + bias ----------------
template<bool GATHER>
__global__ __launch_bounds__(256) void gemm_bias_kernel(
    const void* __restrict__ A, const void* __restrict__ B,
    const void* __restrict__ bias, const int* __restrict__ ids,
    const int* __restrict__ cnt,
    float* __restrict__ C, int M, int N, int K)
{
    const int mode = (*cnt > NDET / 2) ? 1 : 0;
    __shared__ __align__(16) float As[16][68];
    __shared__ __align__(16) float Bs[16][68];
    const int tid = threadIdx.x;
    const int ty = tid >> 4, tx = tid & 15;
    const int m0 = blockIdx.y * 64, n0 = blockIdx.x * 64;
    const int lrow = tid >> 2;
    const int kq   = (tid & 3) * 4;
    const int arow = m0 + lrow;
    const size_t abase = (GATHER ? (size_t)ids[arow] : (size_t)arow) * (size_t)K;
    const int brow = tid >> 4;
    const int bc   = (tid & 15) * 4;
    const int bcol = n0 + bc;
    float acc[4][4] = {};
    for (int k0 = 0; k0 < K; k0 += 16) {
        float4 av = ld4e(A, abase + k0 + kq, mode);
        float4 bv = ld4e(B, (size_t)(k0 + brow) * N + bcol, mode);
        As[kq + 0][lrow] = av.x;
        As[kq + 1][lrow] = av.y;
        As[kq + 2][lrow] = av.z;
        As[kq + 3][lrow] = av.w;
        Bs[brow][bc + 0] = bv.x;
        Bs[brow][bc + 1] = bv.y;
        Bs[brow][bc + 2] = bv.z;
        Bs[brow][bc + 3] = bv.w;
        __syncthreads();
        #pragma unroll
        for (int kk = 0; kk < 16; ++kk) {
            float a[4], bb[4];
            #pragma unroll
            for (int u = 0; u < 4; ++u) a[u] = As[kk][ty * 4 + u];
            #pragma unroll
            for (int v = 0; v < 4; ++v) bb[v] = Bs[kk][tx * 4 + v];
            #pragma unroll
            for (int u = 0; u < 4; ++u)
                #pragma unroll
                for (int v = 0; v < 4; ++v)
                    acc[u][v] = fmaf(a[u], bb[v], acc[u][v]);
        }
        __syncthreads();
    }
    float4 bsv = ld4e(bias, (size_t)(n0 + tx * 4), mode);
    #pragma unroll
    for (int u = 0; u < 4; ++u) {
        float4 o;
        o.x = acc[u][0] + bsv.x; o.y = acc[u][1] + bsv.y;
        o.z = acc[u][2] + bsv.z; o.w = acc[u][3] + bsv.w;
        *(float4*)(C + (size_t)(m0 + ty * 4 + u) * N + n0 + tx * 4) = o;
    }
}

// ---------------- flag-array barrier (64 participants, no RMWs) ----------------
__device__ inline void gbar(int* flags, int b, int k) {
    __atomic_signal_fence(__ATOMIC_SEQ_CST);
    __builtin_amdgcn_s_waitcnt(0);       // drain this wave's stores/atomics
    __syncthreads();                     // all waves drained
    if (threadIdx.x < 64) {
        if (threadIdx.x == 0) stg_a(&flags[b], k);
        for (;;) {
            int v = ldg_a(&flags[threadIdx.x]);
            if (__all(v >= k)) break;
            __builtin_amdgcn_s_sleep(1);
        }
    }
    __syncthreads();
    __atomic_signal_fence(__ATOMIC_SEQ_CST);
}

__device__ inline float wave_red(float acc) {
    #pragma unroll
    for (int m = 1; m < 64; m <<= 1) acc += __shfl_xor(acc, m, 64);
    return acc;
}

// ---------------- persistent scan: ONE barrier/step, partitioned work ----------------
__global__ __launch_bounds__(NT, 1) void lattice_scan(
    const void* __restrict__ W_hh, const void* __restrict__ Ww_hh,
    const void* __restrict__ aW_hh,
    const float* __restrict__ WIb, const float* __restrict__ AWIb,
    const float* __restrict__ WWIb,
    float* __restrict__ zacc, float* __restrict__ csr,
    float* __restrict__ c_buf, int* __restrict__ flags,
    const int* __restrict__ cnt,
    const int* __restrict__ gpos, const int* __restrict__ gslot,
    const unsigned char* __restrict__ gmaskb,
    int* __restrict__ meta_hdr, int* __restrict__ meta_rows,
    void* __restrict__ outp, int Km)
{
    __shared__ __align__(16) float Wa[HB][HD];       // own 8 cols of aW_hh (16 KB)
    __shared__ __align__(16) float cinS[MAXW][HD];   // staged cin rows (32 KB)
    __shared__ __align__(16) float zwFull[TH3];      // full word-z (len-2 steps)
    __shared__ __align__(16) float csFull[HD];       // full c_{t-1} (len-2 steps)
    __shared__ float zOwn[6][HB], wwOwn[KWW][3][HB], wiOwn[4][HB];
    __shared__ float hOwn[HB], cOwn[HB], wdot[MAXW][HB];
    __shared__ int mh_l[2], mr_l[2][MAXW];
    __shared__ int mfmt;

    const int b    = blockIdx.x;
    const int tid  = threadIdx.x;
    const int wid  = tid >> 6;
    const int q    = tid & 63;
    const int mode = (*cnt > NDET / 2) ? 1 : 0;
    const int hb0  = b * HB;          // first own h-channel

    // ---- one-time init: z-weights into REGISTERS (6 cols x 8 rows/thread) ----
    float wreg[8][NCOL];
    #pragma unroll
    for (int i = 0; i < NCOL; ++i) {
        int col = tid + NT * i;
        #pragma unroll
        for (int j = 0; j < 8; ++j) {
            wreg[j][i] = (col < TH3)
                ? ld1e(W_hh,  (size_t)(hb0 + j) * TH3 + col, mode)
                : ld1e(Ww_hh, (size_t)(hb0 + j) * TH3 + (col - TH3), mode);
        }
    }
    for (int idx = tid; idx < HB * HD; idx += NT) {
        int ho = idx & (HB - 1), r = idx / HB;
        Wa[ho][r] = ld1e(aW_hh, (size_t)r * HD + hb0 + ho, mode);
    }
    if (tid < HB) { hOwn[tid] = 0.f; cOwn[tid] = 0.f; }
    if (tid == 0) mfmt = 0;
    __syncthreads();
    {   // mask storage width: nonzero byte at i%4!=0 => u8/bool storage
        int any = 0;
        int tot = SEQ * Km;
        for (int i = tid; i < tot; i += NT)
            if ((i & 3) && gmaskb[i]) any = 1;
        if (any) mfmt = 1;
    }
    __syncthreads();
    const int maskfmt = mfmt;
    const int* gmi = (const int*)gmaskb;

    // ---- one-time metadata precompute: rows packed (p<<2)|sl ----
    if (tid < SPB) {
        int t = b * SPB + tid;
        int nv = 0;
        for (int k = 0; k < Km; ++k) {
            int mv = maskfmt ? (int)gmaskb[t * Km + k] : gmi[t * Km + k];
            if (!mv) continue;
            int p = gpos[t * Km + k], sl = gslot[t * Km + k];
            if (p < 0 || p >= t || sl < 0 || sl >= KWW) continue;
            if (nv < MAXW) { stg_a(&meta_rows[t * MAXW + nv], (p << 2) | sl); nv++; }
        }
        stg_a(&meta_hdr[t], nv);
    }
    gbar(flags, b, 1);   // publish metadata

    // meta for step 0 (plain loads: immutable after barrier)
    if (tid == 0) mh_l[0] = ldg_a(&meta_hdr[0]);
    if (tid < MAXW) mr_l[0][tid] = ldg_a(&meta_rows[tid]);
    __syncthreads();

    for (int t = 0; t < SEQ; ++t) {
        const int par = t & 1;
        const int rd = t % 3, ad = (t + 1) % 3, zr = (t + 2) % 3;
        float* zrd = zacc + rd * ZT;
        float* zad = zacc + ad * ZT;
        float* zzr = zacc + zr * ZT;

        const int nv = mh_l[par];
        // any len-2 word (created this step, consumed this step)?
        bool anyl2 = false;
        for (int vi = 0; vi < nv; ++vi)
            if ((mr_l[par][vi] >> 2) == t - 1) anyl2 = true;

        // ===== window: batched loads -> LDS =====
        // own z cols (48 sc loads)
        if (tid < 6 * HB) {
            int g = tid >> 3, ho = tid & (HB - 1);
            zOwn[g][ho] = ldg_a(&zrd[g * HD + hb0 + ho]);
        }
        // own WI/AWI rows (plain: immutable)
        if (tid < 4 * HB) {
            int g = tid >> 3, ho = tid & (HB - 1);
            wiOwn[g][ho] = (g < 3) ? WIb[(size_t)t * TH3 + g * HD + hb0 + ho]
                                   : AWIb[(size_t)t * HD + hb0 + ho];
        }
        // own WWI rows for cells born at t-1 (plain)
        if (t > 0 && tid < KWW * 3 * HB) {
            int sl = tid / (3 * HB), g = (tid / HB) % 3, ho = tid & (HB - 1);
            wwOwn[sl][g][ho] =
                WWIb[(size_t)((t - 1) * KWW + sl) * TH3 + g * HD + hb0 + ho];
        }
        // far cin rows -> cinS (plain float4: c_buf rows are write-once)
        {
            int g = tid >> 5, l = tid & 31;
            if (g < nv) {
                int e = mr_l[par][g], p = e >> 2, sl = e & 3;
                if (p <= t - 2) {
                    const float4* src =
                        (const float4*)(c_buf + (size_t)(p * KWW + sl) * HD);
                    float4* dst = (float4*)&cinS[g][0];
                    #pragma unroll
                    for (int i = 0; i < 4; ++i) dst[l + 32 * i] = src[l + 32 * i];
                }
            }
        }
        // len-2 support: full word-z + full c_{t-1} (sc; ~20% of steps)
        if (anyl2) {
            #pragma unroll
            for (int i = 0; i < 3; ++i)
                zwFull[tid + HD * i] = ldg_a(&zrd[TH3 + tid + HD * i]);
            csFull[tid] = ldg_a(&csr[((t - 1) & 1) * HD + tid]);
        }
        // prefetch next meta (sc-written at init, read-after-barrier)
        if (t + 1 < SEQ) {
            if (tid == 0) mh_l[par ^ 1] = ldg_a(&meta_hdr[t + 1]);
            if (tid < MAXW)
                mr_l[par ^ 1][tid] = ldg_a(&meta_rows[(size_t)(t + 1) * MAXW + tid]);
        }
        __syncthreads();

        // ===== cells born at t-1: own 8-ch slice -> c_buf =====
        if (t > 0 && tid < KWW * HB) {
            int sl = tid >> 3, ho = tid & (HB - 1);
            float cv = sigf(wwOwn[sl][0][ho] + zOwn[3][ho]) * cOwn[ho]
                     + sigf(wwOwn[sl][1][ho] + zOwn[4][ho])
                       * tanhf(wwOwn[sl][2][ho] + zOwn[5][ho]);
            stg_a(&c_buf[(size_t)((t - 1) * KWW + sl) * HD + hb0 + ho], cv);
        }
        // ===== len-2 recompute: full cell into cinS[vi] =====
        if (anyl2) {
            for (int vi = 0; vi < nv; ++vi) {
                int e = mr_l[par][vi], p = e >> 2, sl = e & 3;
                if (p != t - 1) continue;
                const float* wrow = WWIb + (size_t)((t - 1) * KWW + sl) * TH3;
                cinS[vi][tid] = sigf(wrow[tid] + zwFull[tid]) * csFull[tid]
                              + sigf(wrow[HD + tid] + zwFull[HD + tid])
                                * tanhf(wrow[2 * HD + tid] + zwFull[2 * HD + tid]);
            }
        }
        __syncthreads();

        // ===== alpha dots: nv*8 wave-jobs, stride-64 conflict-free =====
        if (nv > 0) {
            for (int jj = wid; jj < nv * HB; jj += 8) {
                int vi = jj >> 3, ho = jj & (HB - 1);
                float acc = 0.f;
                #pragma unroll
                for (int i = 0; i < 8; ++i)
                    acc += cinS[vi][q + 64 * i] * Wa[ho][q + 64 * i];
                acc = wave_red(acc);
                if (q == 0) wdot[vi][ho] = acc;
            }
        }
        __syncthreads();

        // ===== merge: own 8 channels =====
        if (tid < HB) {
            int ho = tid;
            float gi = sigf(zOwn[0][ho] + wiOwn[0][ho]);
            float go = sigf(zOwn[1][ho] + wiOwn[1][ho]);
            float gg = tanhf(zOwn[2][ho] + wiOwn[2][ho]);
            float c1;
            if (nv > 0) {
                float wiE = expf(gi);
                float num = wiE * gg, den = wiE;
                for (int vi = 0; vi < nv; ++vi) {
                    float wa = expf(sigf(wiOwn[3][ho] + wdot[vi][ho]));
                    num += wa * cinS[vi][hb0 + ho];
                    den += wa;
                }
                c1 = num / den;
            } else {
                c1 = (1.f - gi) * cOwn[ho] + gi * gg;
            }
            float h1 = go * tanhf(c1);
            cOwn[ho] = c1;
            hOwn[ho] = h1;
            stg_a(&csr[par * HD + hb0 + ho], c1);
            if (mode) {
                unsigned short* o = (unsigned short*)outp;
                o[(size_t)t * HD + hb0 + ho] = f2bf(h1);
                o[(size_t)SEQ * HD + (size_t)t * HD + hb0 + ho] = f2bf(c1);
            } else {
                float* o = (float*)outp;
                o[(size_t)t * HD + hb0 + ho] = h1;
                o[(size_t)SEQ * HD + (size_t)t * HD + hb0 + ho] = c1;
            }
        }
        __syncthreads();

        // ===== partial z_t: 48 reg-FMA + 6 atomic adds; zero rotation buf =====
        {
            float hv[8];
            #pragma unroll
            for (int j = 0; j < 8; ++j) hv[j] = hOwn[j];   // LDS broadcast
            #pragma unroll
            for (int i = 0; i < NCOL; ++i) {
                float p = 0.f;
                #pragma unroll
                for (int j = 0; j < 8; ++j) p = fmaf(hv[j], wreg[j][i], p);
                atomicAdd(&zad[tid + NT * i], p);
            }
            if (tid < ZC) stg_a(&zzr[b * ZC + tid], 0.f);
        }

        // ===== single rendezvous =====
        gbar(flags, b, t + 2);
    }
}

extern "C" void kernel_launch(void* const* d_in, const int* in_sizes, int n_in,
                              void* d_out, int out_size, void* d_ws, size_t ws_size,
                              hipStream_t stream) {
    const void* x     = d_in[0];
    const void* W_ih  = d_in[1];
    const void* W_hh  = d_in[2];
    const void* bb    = d_in[3];
    const void* aW_ih = d_in[4];
    const void* aW_hh = d_in[5];
    const void* ab    = d_in[6];
    const void* Ww_ih = d_in[7];
    const void* Ww_hh = d_in[8];
    const void* bw    = d_in[9];
    const void* wemb  = d_in[10];
    const int* wids  = (const int*)d_in[11];
    const int* gpos  = (const int*)d_in[12];
    const int* gslot = (const int*)d_in[13];
    const unsigned char* gmask = (const unsigned char*)d_in[14];

    int Km = in_sizes[12] / SEQ;
    if (Km > 32) Km = 32;
    if (ws_size < WS_END) return;

    char* ws = (char*)d_ws;
    int*   flags = (int*)(ws + WS_FLAGS);
    int*   cnt   = (int*)(ws + WS_CNT);
    float* zacc  = (float*)(ws + WS_ZACC);
    float* csr   = (float*)(ws + WS_CS);
    float* c_buf = (float*)(ws + WS_CBUF);
    int*   mhdr  = (int*)(ws + WS_MHDR);
    int*   mrows = (int*)(ws + WS_MROWS);
    float* WIb   = (float*)(ws + WS_WIB);
    float* AWIb  = (float*)(ws + WS_AWIB);
    float* WWIb  = (float*)(ws + WS_WWIB);

    hipMemsetAsync(d_ws, 0, WS_ZEROSZ, stream);
    detect_kernel<<<1, 256, 0, stream>>>((const unsigned int*)W_ih, cnt);
    gemm_bias_kernel<false><<<dim3(TH3 / 64, SEQ / 64), 256, 0, stream>>>(
        x, W_ih, bb, nullptr, cnt, WIb, SEQ, TH3, HD);
    gemm_bias_kernel<false><<<dim3(HD / 64, SEQ / 64), 256, 0, stream>>>(
        x, aW_ih, ab, nullptr, cnt, AWIb, SEQ, HD, HD);
    gemm_bias_kernel<true><<<dim3(TH3 / 64, (SEQ * KWW) / 64), 256, 0, stream>>>(
        wemb, Ww_ih, bw, wids, cnt, WWIb, SEQ * KWW, TH3, HD);
    lattice_scan<<<GRID, NT, 0, stream>>>(
        W_hh, Ww_hh, aW_hh, WIb, AWIb, WWIb,
        zacc, csr, c_buf, flags, cnt,
        gpos, gslot, gmask, mhdr, mrows, d_out, Km);
}